// Round 7
// baseline (241.953 us; speedup 1.0000x reference)
//
#include <hip/hip_runtime.h>
#include <hip/hip_bf16.h>
#include <cstdint>

#define S_LEN 1024
#define DIM   1024
#define NH    16
#define HD    64
#define EH    64
#define QB    4      // q rows per mix_av WG
#define KC    64     // k per chunk
#define NCH   16     // chunks

typedef __attribute__((ext_vector_type(8))) short short8v;  // 8 bf16
typedef __attribute__((ext_vector_type(4))) float f32x4;

static __device__ __forceinline__ short f2bf(float f) {
  union { float f; uint32_t u; } v; v.f = f;
  const uint32_t r = v.u + 0x7FFF + ((v.u >> 16) & 1);   // RNE
  return (short)(r >> 16);
}
static __device__ __forceinline__ float bf2f(short s) {
  union { uint32_t u; float f; } v; v.u = ((uint32_t)(uint16_t)s) << 16;
  return v.f;
}
static __device__ __forceinline__ uint32_t packbf(float a, float b) {
  return (uint32_t)(uint16_t)f2bf(a) | ((uint32_t)(uint16_t)f2bf(b) << 16);
}

// ---------------------------------------------------------------------------
// prep: {x,qkv_w,proj_w -> bf16} + {out = proj_b broadcast} + {Vsum = 0}
// ---------------------------------------------------------------------------
__global__ __launch_bounds__(256) void prep(
    const float* __restrict__ x, const float* __restrict__ qw,
    const float* __restrict__ pw, const float* __restrict__ proj_b,
    short* __restrict__ xb, short* __restrict__ wqb, short* __restrict__ wpb,
    float* __restrict__ out, float* __restrict__ Vsum)
{
  const int i = blockIdx.x * 256 + threadIdx.x;
  if (i < 655360) {
    const float* s; short* d; int j = i;
    if (j < 131072)       { s = x;  d = xb; }
    else if (j < 524288)  { j -= 131072; s = qw; d = wqb; }
    else                  { j -= 524288; s = pw; d = wpb; }
    const float4 a = ((const float4*)s)[2 * j];
    const float4 b = ((const float4*)s)[2 * j + 1];
    short8v o;
    o[0] = f2bf(a.x); o[1] = f2bf(a.y); o[2] = f2bf(a.z); o[3] = f2bf(a.w);
    o[4] = f2bf(b.x); o[5] = f2bf(b.y); o[6] = f2bf(b.z); o[7] = f2bf(b.w);
    *(short8v*)(d + 8 * (size_t)j) = o;
  } else if (i < 917504) {
    const int j = i - 655360;           // 262144 float4s
    ((float4*)out)[j] = ((const float4*)proj_b)[j & 255];
  } else if (i < 918528) {
    Vsum[i - 917504] = 0.f;             // 1024 floats
  }
}

// ---------------------------------------------------------------------------
// Vt[h][d][k] = V[h][k][d]; also Vsum[h][d] += partial col-sums (f32 atomics).
// ---------------------------------------------------------------------------
__global__ __launch_bounds__(256) void transpose_v(
    const short* __restrict__ qkvb, short* __restrict__ Vt,
    float* __restrict__ Vsum)
{
  const int h  = blockIdx.y;
  const int k0 = blockIdx.x * 32;
  const int d  = threadIdx.x & 63;
  const int kw = threadIdx.x >> 6;                   // 0..3
  const short* src = qkvb + 2048 + h * 64 + d;
  short8v o;
  float s = 0.f;
  #pragma unroll
  for (int j = 0; j < 8; ++j) {
    o[j] = src[(size_t)(k0 + kw * 8 + j) * 3072];
    s += bf2f(o[j]);
  }
  *(short8v*)(Vt + ((size_t)h * 64 + d) * 1024 + k0 + kw * 8) = o;
  atomicAdd(&Vsum[h * 64 + d], s);
}

// ---------------------------------------------------------------------------
// bf16 MFMA GEMM (NT): C[m][n] = alpha * sum_k A[m][k] * B[n][k] (+bias)
// 128x64 tile, BK=64, 4 waves (2x2), wave tile 64x32 (4x2 16x16x32 frags).
// LDS XOR-swizzle on staging; CMODE 0: bf16 store via LDS-bounce WIDE stores
// (r6 lesson: 2B scatter stores -> write-allocate amplification).
// CMODE 2: f32 atomicAdd. NSPLIT: K split over blockIdx.z % NSPLIT.
// ---------------------------------------------------------------------------
template<int NSPLIT, int CMODE>
__global__ __launch_bounds__(256) void gemm_v2(
    const short* __restrict__ A, int lda, long long aStride,
    const short* __restrict__ B, int ldb, long long bStride,
    void* __restrict__ C_, int ldc, long long cStride,
    int K, float alpha, const float* __restrict__ bias)
{
  __shared__ short sbuf[128 * 64 + 64 * 64];   // As | Bs ; epilogue reuses as Cb
  short* As = sbuf;
  short* Bs = sbuf + 128 * 64;

  const int z = blockIdx.z, batch = z / NSPLIT, split = z % NSPLIT;
  A += (size_t)batch * aStride;
  B += (size_t)batch * bStride;

  const int t = threadIdx.x, wid = t >> 6, lane = t & 63;
  const int wr = wid >> 1, wc = wid & 1;
  const int fr = lane & 15, kg = lane >> 4;
  const int m0 = blockIdx.y * 128, n0 = blockIdx.x * 64;
  const int klen = K / NSPLIT, kbeg = split * klen;

  f32x4 acc[4][2] = {};

  for (int k0 = kbeg; k0 < kbeg + klen; k0 += 64) {
    #pragma unroll
    for (int i = 0; i < 4; ++i) {               // A: 1024 16B pieces
      const int p = t + i * 256;
      const int row = p >> 3, pc = p & 7;
      *(short8v*)&As[row * 64 + ((pc ^ (row & 7)) << 3)] =
          *(const short8v*)(A + (size_t)(m0 + row) * lda + k0 + pc * 8);
    }
    #pragma unroll
    for (int i = 0; i < 2; ++i) {               // B: 512 pieces
      const int p = t + i * 256;
      const int row = p >> 3, pc = p & 7;
      *(short8v*)&Bs[row * 64 + ((pc ^ (row & 7)) << 3)] =
          *(const short8v*)(B + (size_t)(n0 + row) * ldb + k0 + pc * 8);
    }
    __syncthreads();

    #pragma unroll
    for (int sub = 0; sub < 2; ++sub) {
      short8v af[4], bg[2];
      #pragma unroll
      for (int ms = 0; ms < 4; ++ms) {
        const int row = wr * 64 + ms * 16 + fr;
        af[ms] = *(const short8v*)&As[row * 64 + (((sub * 4 + kg) ^ (row & 7)) << 3)];
      }
      #pragma unroll
      for (int ns = 0; ns < 2; ++ns) {
        const int row = wc * 32 + ns * 16 + fr;
        bg[ns] = *(const short8v*)&Bs[row * 64 + (((sub * 4 + kg) ^ (row & 7)) << 3)];
      }
      #pragma unroll
      for (int ms = 0; ms < 4; ++ms)
        #pragma unroll
        for (int ns = 0; ns < 2; ++ns)
          acc[ms][ns] = __builtin_amdgcn_mfma_f32_16x16x32_bf16(
              af[ms], bg[ns], acc[ms][ns], 0, 0, 0);
    }
    __syncthreads();
  }

  if constexpr (CMODE == 0) {
    // wide-store epilogue: frags -> Cb[128][72] -> coalesced short8 rows
    short* Cb = sbuf;
    #pragma unroll
    for (int ms = 0; ms < 4; ++ms)
      #pragma unroll
      for (int ns = 0; ns < 2; ++ns) {
        const int col = wc * 32 + ns * 16 + fr;
        const float bv = bias ? bias[n0 + col] : 0.f;
        #pragma unroll
        for (int j = 0; j < 4; ++j) {
          const int row = wr * 64 + ms * 16 + kg * 4 + j;
          Cb[row * 72 + col] = f2bf(acc[ms][ns][j] * alpha + bv);
        }
      }
    __syncthreads();
    short* Cg = (short*)C_ + (size_t)batch * cStride;
    #pragma unroll
    for (int i = 0; i < 4; ++i) {
      const int p = t + i * 256;                // 1024 short8s
      const int row = p >> 3, c8 = (p & 7) << 3;
      *(short8v*)(Cg + (size_t)(m0 + row) * ldc + n0 + c8) =
          *(const short8v*)&Cb[row * 72 + c8];
    }
  } else {
    float* Cg = (float*)C_ + (size_t)batch * cStride;
    #pragma unroll
    for (int ms = 0; ms < 4; ++ms)
      #pragma unroll
      for (int ns = 0; ns < 2; ++ns) {
        const int col = n0 + wc * 32 + ns * 16 + fr;
        #pragma unroll
        for (int j = 0; j < 4; ++j) {
          const int row = m0 + wr * 64 + ms * 16 + kg * 4 + j;
          atomicAdd(Cg + (size_t)row * ldc + col, acc[ms][ns][j] * alpha);
        }
      }
  }
}

// ---------------------------------------------------------------------------
// scores_v2: Sb[h][q][k] = bf16((q_h.k_h)/8). K=64, NT, fragments direct
// from L2-resident qkvb (no staging reuse exists); epilogue LDS-bounce to
// full-line stores. 128x64 tile, 4 waves.
// ---------------------------------------------------------------------------
__global__ __launch_bounds__(256) void scores_v2(
    const short* __restrict__ qkvb, short* __restrict__ Sb)
{
  __shared__ short Cb[128][72];
  const int h = blockIdx.z;
  const int t = threadIdx.x, wid = t >> 6, lane = t & 63;
  const int wr = wid >> 1, wc = wid & 1;
  const int fr = lane & 15, kg = lane >> 4;
  const int m0 = blockIdx.y * 128, n0 = blockIdx.x * 64;

  const short* Aq = qkvb + h * 64;            // q rows
  const short* Bk = qkvb + 1024 + h * 64;     // k rows

  f32x4 acc[4][2] = {};
  #pragma unroll
  for (int sub = 0; sub < 2; ++sub) {
    const int d8 = (sub * 4 + kg) * 8;
    short8v af[4], bg[2];
    #pragma unroll
    for (int ms = 0; ms < 4; ++ms)
      af[ms] = *(const short8v*)(Aq + (size_t)(m0 + wr * 64 + ms * 16 + fr) * 3072 + d8);
    #pragma unroll
    for (int ns = 0; ns < 2; ++ns)
      bg[ns] = *(const short8v*)(Bk + (size_t)(n0 + wc * 32 + ns * 16 + fr) * 3072 + d8);
    #pragma unroll
    for (int ms = 0; ms < 4; ++ms)
      #pragma unroll
      for (int ns = 0; ns < 2; ++ns)
        acc[ms][ns] = __builtin_amdgcn_mfma_f32_16x16x32_bf16(
            af[ms], bg[ns], acc[ms][ns], 0, 0, 0);
  }

  #pragma unroll
  for (int ms = 0; ms < 4; ++ms)
    #pragma unroll
    for (int ns = 0; ns < 2; ++ns) {
      const int col = wc * 32 + ns * 16 + fr;
      #pragma unroll
      for (int j = 0; j < 4; ++j)
        Cb[wr * 64 + ms * 16 + kg * 4 + j][col] = f2bf(acc[ms][ns][j] * 0.125f);
    }
  __syncthreads();
  short* Ch = Sb + ((size_t)h << 20);
  #pragma unroll
  for (int i = 0; i < 4; ++i) {
    const int p = t + i * 256;
    const int row = p >> 3, c8 = (p & 7) << 3;
    *(short8v*)(Ch + (size_t)(m0 + row) * 1024 + n0 + c8) =
        *(const short8v*)&Cb[row][c8];
  }
}

// ---------------------------------------------------------------------------
// mix_av: fused mix1 + softmax(no-max) + mix2 + AV. WG = 512 thr (8 waves),
// owns QB=4 q rows; grid 256. P_mix never touches global memory.
//   pass 1: for 16 k-chunks: stage St[qk'][h], z = mfma(ap1,St), accumulate
//           per-lane l partials; butterfly + LDS-combine -> L[e][q] = ln(l).
//   pass 2: restage, z, P_hat = exp(z - L), Pt wave-bounce -> mix2 MFMA ->
//           Pm[h][q][kchunk] LDS -> AV MFMA vs Vt (L2-hot) -> acc regs.
//   epilogue: out[q][h*64+d] = acc + ap2_b[h]*Vsum[h][d], LDS-bounce wide store.
// Wave split: (qv = w&3, half = w>>2): z/mix2 tiles t = 4qv+2half+{0,1};
// AV: h = {2w, 2w+1}. AV A-frag rows 4..15 are zero-pad (M=4 real rows).
// ---------------------------------------------------------------------------
__global__ __launch_bounds__(512) void mix_av(
    const short* __restrict__ Sb, const short* __restrict__ Vt,
    const float* __restrict__ ap1_w, const float* __restrict__ ap2_w,
    const float* __restrict__ ap2_b, const float* __restrict__ Vsum,
    short* __restrict__ attnb)
{
  __shared__ short St[QB * KC][24];     // [qk'][h], 48B rows (16B-aligned)
  __shared__ short Pm[NH][QB][72];      // [h][q][k-in-chunk], 144B rows
  __shared__ short Pt[8][16][72];       // wave-private mix2 operand bounce
  __shared__ float l_acc[2][EH][QB];
  __shared__ short Ob[QB][1032];        // output bounce (2064B rows, aligned)

  const int t = threadIdx.x;
  const int w = t >> 6, lane = t & 63;
  const int kg = lane >> 4, fr = lane & 15;
  const int qv = w & 3, half = w >> 2;
  const int q0 = blockIdx.x * QB;

  if (t < 2 * EH * QB) ((float*)l_acc)[t] = 0.f;   // 512 == 2*64*4

  // staging coords: thread -> (h, q, k8) ; 512 thr x short8 = 16h*4q*64k
  const int sh = t & 15, sq = (t >> 4) & 3, sk8 = (t >> 6) << 3;
  const short* sp = Sb + ((size_t)sh << 20) + ((size_t)(q0 + sq) << 10);

  // ap1 A-frags: row e = ms*16+fr, k-dim h = kg*8..+8 (zero for kg>=2)
  short8v af1[4];
  #pragma unroll
  for (int ms = 0; ms < 4; ++ms) {
    short8v v;
    #pragma unroll
    for (int j = 0; j < 8; ++j) v[j] = 0;
    if (kg < 2) {
      const int e = ms * 16 + fr;
      #pragma unroll
      for (int j = 0; j < 8; ++j) v[j] = f2bf(ap1_w[e * 16 + kg * 8 + j]);
    }
    af1[ms] = v;
  }
  // ap2 A-frags (plain; P_hat is pre-normalized): row h = fr, k-dim e
  short8v af2[2];
  #pragma unroll
  for (int half2 = 0; half2 < 2; ++half2) {
    short8v v;
    #pragma unroll
    for (int j = 0; j < 8; ++j)
      v[j] = f2bf(ap2_w[fr * 64 + half2 * 32 + kg * 8 + j]);
    af2[half2] = v;
  }

  const f32x4 zc = {0.f, 0.f, 0.f, 0.f};

  // ================= pass 1: l =================
  float l16[4][4] = {};
  for (int c = 0; c < NCH; ++c) {
    const short8v v = *(const short8v*)(sp + c * KC + sk8);
    __syncthreads();                       // St consumers of chunk c-1 done
    #pragma unroll
    for (int j = 0; j < 8; ++j) St[sq * 64 + sk8 + j][sh] = v[j];
    __syncthreads();                       // St ready
    #pragma unroll
    for (int tt = 0; tt < 2; ++tt) {
      const int tile = 4 * qv + 2 * half + tt;
      short8v bg;
      #pragma unroll
      for (int j = 0; j < 8; ++j) bg[j] = 0;
      if (kg < 2) bg = *(const short8v*)&St[tile * 16 + fr][kg * 8];
      #pragma unroll
      for (int ms = 0; ms < 4; ++ms) {
        const f32x4 zv = __builtin_amdgcn_mfma_f32_16x16x32_bf16(af1[ms], bg, zc, 0, 0, 0);
        #pragma unroll
        for (int j = 0; j < 4; ++j) l16[ms][j] += __expf(zv[j]);
      }
    }
  }
  #pragma unroll
  for (int ms = 0; ms < 4; ++ms)
    #pragma unroll
    for (int j = 0; j < 4; ++j) {
      float v = l16[ms][j];
      v += __shfl_xor(v, 1); v += __shfl_xor(v, 2);
      v += __shfl_xor(v, 4); v += __shfl_xor(v, 8);
      l16[ms][j] = v;
    }
  __syncthreads();                         // last chunk's St reads done (paranoia) / l_acc zero visible
  if (fr == 0)
    #pragma unroll
    for (int ms = 0; ms < 4; ++ms)
      #pragma unroll
      for (int j = 0; j < 4; ++j)
        l_acc[half][ms * 16 + kg * 4 + j][qv] = l16[ms][j];
  __syncthreads();
  if (t < 256) {
    const int e = t >> 2, q = t & 3;
    l_acc[0][e][q] = logf(l_acc[0][e][q] + l_acc[1][e][q]);
  }
  __syncthreads();
  float Lreg[4][4];
  #pragma unroll
  for (int ms = 0; ms < 4; ++ms)
    #pragma unroll
    for (int j = 0; j < 4; ++j)
      Lreg[ms][j] = l_acc[0][ms * 16 + kg * 4 + j][qv];

  // ================= pass 2: P_hat -> mix2 -> AV =================
  f32x4 avacc[2][4] = {};                  // [hh][dblk]
  const int h0 = w * 2;
  for (int c = 0; c < NCH; ++c) {
    const short8v v = *(const short8v*)(sp + c * KC + sk8);
    __syncthreads();                       // prev AV (Pm reads) + St reads done
    #pragma unroll
    for (int j = 0; j < 8; ++j) St[sq * 64 + sk8 + j][sh] = v[j];
    __syncthreads();                       // St ready
    #pragma unroll
    for (int tt = 0; tt < 2; ++tt) {
      const int tile = 4 * qv + 2 * half + tt;
      short8v bg;
      #pragma unroll
      for (int j = 0; j < 8; ++j) bg[j] = 0;
      if (kg < 2) bg = *(const short8v*)&St[tile * 16 + fr][kg * 8];
      #pragma unroll
      for (int ms = 0; ms < 4; ++ms) {
        const f32x4 zv = __builtin_amdgcn_mfma_f32_16x16x32_bf16(af1[ms], bg, zc, 0, 0, 0);
        const float p0 = __expf(zv[0] - Lreg[ms][0]);
        const float p1 = __expf(zv[1] - Lreg[ms][1]);
        const float p2 = __expf(zv[2] - Lreg[ms][2]);
        const float p3 = __expf(zv[3] - Lreg[ms][3]);
        *(uint32_t*)&Pt[w][fr][ms * 16 + kg * 4]     = packbf(p0, p1);
        *(uint32_t*)&Pt[w][fr][ms * 16 + kg * 4 + 2] = packbf(p2, p3);
      }
      f32x4 o = zc;
      const short8v pv0 = *(const short8v*)&Pt[w][fr][kg * 8];
      const short8v pv1 = *(const short8v*)&Pt[w][fr][32 + kg * 8];
      o = __builtin_amdgcn_mfma_f32_16x16x32_bf16(af2[0], pv0, o, 0, 0, 0);
      o = __builtin_amdgcn_mfma_f32_16x16x32_bf16(af2[1], pv1, o, 0, 0, 0);
      const int kk = (2 * half + tt) * 16 + fr;
      #pragma unroll
      for (int jj = 0; jj < 4; ++jj)
        Pm[kg * 4 + jj][qv][kk] = f2bf(o[jj]);
    }
    __syncthreads();                       // Pm ready
    #pragma unroll
    for (int hh = 0; hh < 2; ++hh) {
      const int h = h0 + hh;
      #pragma unroll
      for (int chain = 0; chain < 2; ++chain) {
        short8v pa;
        #pragma unroll
        for (int j = 0; j < 8; ++j) pa[j] = 0;
        if (fr < QB) pa = *(const short8v*)&Pm[h][fr][chain * 32 + kg * 8];
        #pragma unroll
        for (int dblk = 0; dblk < 4; ++dblk) {
          const short8v vb = *(const short8v*)(
              Vt + ((size_t)h * 64 + dblk * 16 + fr) * 1024 + c * KC + chain * 32 + kg * 8);
          avacc[hh][dblk] = __builtin_amdgcn_mfma_f32_16x16x32_bf16(
              pa, vb, avacc[hh][dblk], 0, 0, 0);
        }
      }
    }
  }

  // ================= epilogue =================
  __syncthreads();
  #pragma unroll
  for (int hh = 0; hh < 2; ++hh) {
    const int h = h0 + hh;
    const float b2 = ap2_b[h];
    #pragma unroll
    for (int dblk = 0; dblk < 4; ++dblk) {
      if (kg == 0) {
        const int d = dblk * 16 + fr;
        const float vs = Vsum[h * 64 + d];
        #pragma unroll
        for (int j = 0; j < 4; ++j)
          Ob[j][h * 64 + d] = f2bf(avacc[hh][dblk][j] + b2 * vs);
      }
    }
  }
  __syncthreads();
  {
    const int row = t >> 7, c8 = (t & 127) << 3;   // 512 short8s
    *(short8v*)(attnb + ((size_t)(q0 + row) << 10) + c8) =
        *(const short8v*)&Ob[row][c8];
  }
}

// ---------------------------------------------------------------------------
extern "C" void kernel_launch(void* const* d_in, const int* in_sizes, int n_in,
                              void* d_out, int out_size, void* d_ws, size_t ws_size,
                              hipStream_t stream)
{
  (void)in_sizes; (void)n_in; (void)out_size; (void)ws_size;

  const float* x      = (const float*)d_in[0];
  const float* qkv_w  = (const float*)d_in[1];
  const float* qkv_b  = (const float*)d_in[2];
  const float* proj_w = (const float*)d_in[3];
  const float* proj_b = (const float*)d_in[4];
  const float* ap1_w  = (const float*)d_in[5];
  const float* ap2_w  = (const float*)d_in[7];
  const float* ap2_b  = (const float*)d_in[8];
  float* out = (float*)d_out;

  // ws: xb[1M] wqb[3M] wpb[1M] qkvb[3M] Sb[16M] Vt[1M] shorts | Vsum[1K] f32
  // attnb reuses xb (dead after qkv GEMM).
  short* xb    = (short*)d_ws;
  short* wqb   = xb   + (size_t)(1 << 20);
  short* wpb   = wqb  + (size_t)3 * (1 << 20);
  short* qkvb  = wpb  + (size_t)(1 << 20);
  short* Sb    = qkvb + (size_t)3 * (1 << 20);
  short* Vt    = Sb   + (size_t)16 * (1 << 20);
  float* Vsum  = (float*)(Vt + (size_t)(1 << 20));
  short* attnb = xb;

  // 0) converts + out prefill + Vsum zero
  prep<<<dim3(3588), 256, 0, stream>>>(x, qkv_w, proj_w, proj_b,
                                       xb, wqb, wpb, out, Vsum);

  // 1) qkvb = bf16(x @ qkv_w^T + qkv_b)        [1024 x 3072], K=1024
  gemm_v2<1, 0><<<dim3(48, 8, 1), 256, 0, stream>>>(
      xb, DIM, 0, wqb, DIM, 0, qkvb, 3 * DIM, 0, DIM, 1.f, qkv_b);

  // 2) Sb[h] = bf16((q_h.k_h)/8), direct frags + wide stores
  scores_v2<<<dim3(16, 8, NH), 256, 0, stream>>>(qkvb, Sb);

  // 3) Vt + Vsum
  transpose_v<<<dim3(32, NH), 256, 0, stream>>>(qkvb, Vt, Vsum);

  // 4) fused mix1+softmax+mix2+AV -> attnb    (256 WGs x 512 thr)
  mix_av<<<dim3(256), 512, 0, stream>>>(Sb, Vt, ap1_w, ap2_w, ap2_b, Vsum, attnb);

  // 5) out += attnb @ proj_w^T (bias prefilled), K-split 2, atomic
  gemm_v2<2, 2><<<dim3(16, 8, 2), 256, 0, stream>>>(
      attnb, DIM, 0, wpb, DIM, 0, out, DIM, 0, DIM, 1.f, nullptr);
}

// Round 8
// 236.032 us; speedup vs baseline: 1.0251x; 1.0251x over previous
//
#include <hip/hip_runtime.h>
#include <hip/hip_bf16.h>
#include <cstdint>

#define S_LEN 1024
#define DIM   1024
#define NH    16
#define HD    64
#define EH    64

typedef __attribute__((ext_vector_type(8))) short short8v;  // 8 bf16
typedef __attribute__((ext_vector_type(4))) float f32x4;

static __device__ __forceinline__ short f2bf(float f) {
  union { float f; uint32_t u; } v; v.f = f;
  const uint32_t r = v.u + 0x7FFF + ((v.u >> 16) & 1);   // RNE
  return (short)(r >> 16);
}
static __device__ __forceinline__ uint32_t packbf(float a, float b) {
  return (uint32_t)(uint16_t)f2bf(a) | ((uint32_t)(uint16_t)f2bf(b) << 16);
}

// ---------------------------------------------------------------------------
// prep: {x,qkv_w,proj_w -> bf16} + {out = proj_b broadcast}
// ---------------------------------------------------------------------------
__global__ __launch_bounds__(256) void prep(
    const float* __restrict__ x, const float* __restrict__ qw,
    const float* __restrict__ pw, const float* __restrict__ proj_b,
    short* __restrict__ xb, short* __restrict__ wqb, short* __restrict__ wpb,
    float* __restrict__ out)
{
  const int i = blockIdx.x * 256 + threadIdx.x;
  if (i < 655360) {
    const float* s; short* d; int j = i;
    if (j < 131072)       { s = x;  d = xb; }
    else if (j < 524288)  { j -= 131072; s = qw; d = wqb; }
    else                  { j -= 524288; s = pw; d = wpb; }
    const float4 a = ((const float4*)s)[2 * j];
    const float4 b = ((const float4*)s)[2 * j + 1];
    short8v o;
    o[0] = f2bf(a.x); o[1] = f2bf(a.y); o[2] = f2bf(a.z); o[3] = f2bf(a.w);
    o[4] = f2bf(b.x); o[5] = f2bf(b.y); o[6] = f2bf(b.z); o[7] = f2bf(b.w);
    *(short8v*)(d + 8 * (size_t)j) = o;
  } else {
    const int j = i - 655360;           // 262144 float4s
    ((float4*)out)[j] = ((const float4*)proj_b)[j & 255];
  }
}

// ---------------------------------------------------------------------------
// Vt[h][d][k] = V[h][k][d]  (V = qkvb columns 2048..3071)
// ---------------------------------------------------------------------------
__global__ __launch_bounds__(256) void transpose_v(
    const short* __restrict__ qkvb, short* __restrict__ Vt)
{
  const int h  = blockIdx.y;
  const int k0 = blockIdx.x * 32;
  const int d  = threadIdx.x & 63;
  const int kw = threadIdx.x >> 6;                   // 0..3
  const short* src = qkvb + 2048 + h * 64 + d;
  short8v o;
  #pragma unroll
  for (int j = 0; j < 8; ++j)
    o[j] = src[(size_t)(k0 + kw * 8 + j) * 3072];
  *(short8v*)(Vt + ((size_t)h * 64 + d) * 1024 + k0 + kw * 8) = o;
}

// ---------------------------------------------------------------------------
// bf16 MFMA GEMM (NT): C[m][n] = alpha * sum_k A[m][k] * B[n][k] (+bias)
// BMx64 tile (BM 128|64), BK=64, 4 waves (2x2), wave tile (BM/2)x32.
// LDS XOR-swizzle on staging. CMODE 0: bf16 via LDS-bounce wide stores.
// CMODE 2: f32 atomicAdd. NSPLIT: K split over blockIdx.z % NSPLIT.
// ---------------------------------------------------------------------------
template<int BM, int NSPLIT, int CMODE>
__global__ __launch_bounds__(256) void gemm_v2(
    const short* __restrict__ A, int lda, long long aStride,
    const short* __restrict__ B, int ldb, long long bStride,
    void* __restrict__ C_, int ldc, long long cStride,
    int K, float alpha, const float* __restrict__ bias)
{
  constexpr int MS = BM / 32;                  // m-frags per wave / stage iters
  __shared__ short sbuf[(BM + 64) * 64];       // As | Bs ; epilogue reuses as Cb
  short* As = sbuf;
  short* Bs = sbuf + BM * 64;

  const int z = blockIdx.z, batch = z / NSPLIT, split = z % NSPLIT;
  A += (size_t)batch * aStride;
  B += (size_t)batch * bStride;

  const int t = threadIdx.x, wid = t >> 6, lane = t & 63;
  const int wr = wid >> 1, wc = wid & 1;
  const int fr = lane & 15, kg = lane >> 4;
  const int m0 = blockIdx.y * BM, n0 = blockIdx.x * 64;
  const int klen = K / NSPLIT, kbeg = split * klen;

  f32x4 acc[MS][2] = {};

  for (int k0 = kbeg; k0 < kbeg + klen; k0 += 64) {
    #pragma unroll
    for (int i = 0; i < MS; ++i) {              // A: BM*8 16B pieces
      const int p = t + i * 256;
      const int row = p >> 3, pc = p & 7;
      *(short8v*)&As[row * 64 + ((pc ^ (row & 7)) << 3)] =
          *(const short8v*)(A + (size_t)(m0 + row) * lda + k0 + pc * 8);
    }
    #pragma unroll
    for (int i = 0; i < 2; ++i) {               // B: 512 pieces
      const int p = t + i * 256;
      const int row = p >> 3, pc = p & 7;
      *(short8v*)&Bs[row * 64 + ((pc ^ (row & 7)) << 3)] =
          *(const short8v*)(B + (size_t)(n0 + row) * ldb + k0 + pc * 8);
    }
    __syncthreads();

    #pragma unroll
    for (int sub = 0; sub < 2; ++sub) {
      short8v af[MS], bg[2];
      #pragma unroll
      for (int ms = 0; ms < MS; ++ms) {
        const int row = wr * (BM / 2) + ms * 16 + fr;
        af[ms] = *(const short8v*)&As[row * 64 + (((sub * 4 + kg) ^ (row & 7)) << 3)];
      }
      #pragma unroll
      for (int ns = 0; ns < 2; ++ns) {
        const int row = wc * 32 + ns * 16 + fr;
        bg[ns] = *(const short8v*)&Bs[row * 64 + (((sub * 4 + kg) ^ (row & 7)) << 3)];
      }
      #pragma unroll
      for (int ms = 0; ms < MS; ++ms)
        #pragma unroll
        for (int ns = 0; ns < 2; ++ns)
          acc[ms][ns] = __builtin_amdgcn_mfma_f32_16x16x32_bf16(
              af[ms], bg[ns], acc[ms][ns], 0, 0, 0);
    }
    __syncthreads();
  }

  if constexpr (CMODE == 0) {
    // wide-store epilogue: frags -> Cb[BM][72] -> coalesced short8 rows
    short* Cb = sbuf;
    #pragma unroll
    for (int ms = 0; ms < MS; ++ms)
      #pragma unroll
      for (int ns = 0; ns < 2; ++ns) {
        const int col = wc * 32 + ns * 16 + fr;
        const float bv = bias ? bias[n0 + col] : 0.f;
        #pragma unroll
        for (int j = 0; j < 4; ++j) {
          const int row = wr * (BM / 2) + ms * 16 + kg * 4 + j;
          Cb[row * 72 + col] = f2bf(acc[ms][ns][j] * alpha + bv);
        }
      }
    __syncthreads();
    short* Cg = (short*)C_ + (size_t)batch * cStride;
    #pragma unroll
    for (int i = 0; i < MS; ++i) {
      const int p = t + i * 256;                // BM*8 short8s
      const int row = p >> 3, c8 = (p & 7) << 3;
      *(short8v*)(Cg + (size_t)(m0 + row) * ldc + n0 + c8) =
          *(const short8v*)&Cb[row * 72 + c8];
    }
  } else {
    float* Cg = (float*)C_ + (size_t)batch * cStride;
    #pragma unroll
    for (int ms = 0; ms < MS; ++ms)
      #pragma unroll
      for (int ns = 0; ns < 2; ++ns) {
        const int col = n0 + wc * 32 + ns * 16 + fr;
        #pragma unroll
        for (int j = 0; j < 4; ++j) {
          const int row = m0 + wr * (BM / 2) + ms * 16 + kg * 4 + j;
          atomicAdd(Cg + (size_t)row * ldc + col, acc[ms][ns][j] * alpha);
        }
      }
  }
}

// ---------------------------------------------------------------------------
// scores_v2: Sb[h][q][k] = bf16((q_h.k_h)/8). K=64, NT, fragments direct
// from L2-resident qkvb; epilogue LDS-bounce to full-line stores.
// ---------------------------------------------------------------------------
__global__ __launch_bounds__(256) void scores_v2(
    const short* __restrict__ qkvb, short* __restrict__ Sb)
{
  __shared__ short Cb[128][72];
  const int h = blockIdx.z;
  const int t = threadIdx.x, wid = t >> 6, lane = t & 63;
  const int wr = wid >> 1, wc = wid & 1;
  const int fr = lane & 15, kg = lane >> 4;
  const int m0 = blockIdx.y * 128, n0 = blockIdx.x * 64;

  const short* Aq = qkvb + h * 64;            // q rows
  const short* Bk = qkvb + 1024 + h * 64;     // k rows

  f32x4 acc[4][2] = {};
  #pragma unroll
  for (int sub = 0; sub < 2; ++sub) {
    const int d8 = (sub * 4 + kg) * 8;
    short8v af[4], bg[2];
    #pragma unroll
    for (int ms = 0; ms < 4; ++ms)
      af[ms] = *(const short8v*)(Aq + (size_t)(m0 + wr * 64 + ms * 16 + fr) * 3072 + d8);
    #pragma unroll
    for (int ns = 0; ns < 2; ++ns)
      bg[ns] = *(const short8v*)(Bk + (size_t)(n0 + wc * 32 + ns * 16 + fr) * 3072 + d8);
    #pragma unroll
    for (int ms = 0; ms < 4; ++ms)
      #pragma unroll
      for (int ns = 0; ns < 2; ++ns)
        acc[ms][ns] = __builtin_amdgcn_mfma_f32_16x16x32_bf16(
            af[ms], bg[ns], acc[ms][ns], 0, 0, 0);
  }

  #pragma unroll
  for (int ms = 0; ms < 4; ++ms)
    #pragma unroll
    for (int ns = 0; ns < 2; ++ns) {
      const int col = wc * 32 + ns * 16 + fr;
      #pragma unroll
      for (int j = 0; j < 4; ++j)
        Cb[wr * 64 + ms * 16 + kg * 4 + j][col] = f2bf(acc[ms][ns][j] * 0.125f);
    }
  __syncthreads();
  short* Ch = Sb + ((size_t)h << 20);
  #pragma unroll
  for (int i = 0; i < 4; ++i) {
    const int p = t + i * 256;
    const int row = p >> 3, c8 = (p & 7) << 3;
    *(short8v*)(Ch + (size_t)(m0 + row) * 1024 + n0 + c8) =
        *(const short8v*)&Cb[row][c8];
  }
}

// ---------------------------------------------------------------------------
// Talking-heads middle v3 (r6 structure + traffic fixes):
//   - staging reads k-fastest (coalesced 1KB runs per plane)  [was: scattered]
//   - sweep P writes results back INTO St (wave-local rows, u32-packed),
//     then a final unstage phase emits coalesced short8 stores [was: 2B scatter]
// Two sweeps over LDS (no-max softmax, r6-validated), in place on Sb.
// ---------------------------------------------------------------------------
__global__ __launch_bounds__(256, 3) void mix_softmax(
    short* __restrict__ Sb,
    const float* __restrict__ ap1_w,
    const float* __restrict__ ap2_w,
    const float* __restrict__ ap2_b)
{
  __shared__ short St[S_LEN][16];     // 32 KB, [k][h]
  __shared__ short Pt[4][16][72];     // wave-private mix2 operand bounce
  __shared__ float red[4][EH];
  __shared__ float il_tab[EH];

  const int q = blockIdx.x, t = threadIdx.x;
  const int w = t >> 6, lane = t & 63, kg = lane >> 4, fr = lane & 15;
  const size_t qoff = (size_t)q << 10;

  // ---- stage: k-fastest coalesced reads -> packed u32 St writes ----
  #pragma unroll
  for (int it = 0; it < 4; ++it) {
    const int i  = t + it * 256;
    const int k8 = (i & 127) * 8;
    const int hp = i >> 7;
    const short8v v0 = *(const short8v*)(Sb + ((size_t)(2 * hp)     << 20) + qoff + k8);
    const short8v v1 = *(const short8v*)(Sb + ((size_t)(2 * hp + 1) << 20) + qoff + k8);
    #pragma unroll
    for (int j = 0; j < 8; ++j)
      *(uint32_t*)&St[k8 + j][2 * hp] =
          (uint32_t)(uint16_t)v0[j] | ((uint32_t)(uint16_t)v1[j] << 16);
  }

  // ---- ap1 A-frags: row e = ms*16+fr, k-dim h = kg*8..+8 (zero kg>=2) ----
  short8v af1[4];
  #pragma unroll
  for (int ms = 0; ms < 4; ++ms) {
    short8v v;
    #pragma unroll
    for (int j = 0; j < 8; ++j) v[j] = 0;
    if (kg < 2) {
      const int e = ms * 16 + fr;
      #pragma unroll
      for (int j = 0; j < 8; ++j) v[j] = f2bf(ap1_w[e * 16 + kg * 8 + j]);
    }
    af1[ms] = v;
  }
  float b2[4];
  #pragma unroll
  for (int j = 0; j < 4; ++j) b2[j] = ap2_b[kg * 4 + j];
  __syncthreads();

  const int kbase = w * 256;
  const f32x4 zc = {0.f, 0.f, 0.f, 0.f};

  // ---- sweep L: l = sum_k exp(z)  (no max: logits bounded) ----
  float ls[4][4] = {};
  for (int s = 0; s < 16; ++s) {
    const int krow = kbase + s * 16 + fr;
    short8v bg;
    #pragma unroll
    for (int j = 0; j < 8; ++j) bg[j] = 0;
    if (kg < 2) bg = *(const short8v*)&St[krow][kg * 8];
    #pragma unroll
    for (int ms = 0; ms < 4; ++ms) {
      const f32x4 zv = __builtin_amdgcn_mfma_f32_16x16x32_bf16(af1[ms], bg, zc, 0, 0, 0);
      #pragma unroll
      for (int j = 0; j < 4; ++j) ls[ms][j] += __expf(zv[j]);
    }
  }
  #pragma unroll
  for (int ms = 0; ms < 4; ++ms)
    #pragma unroll
    for (int j = 0; j < 4; ++j) {
      float v = ls[ms][j];
      v += __shfl_xor(v, 1); v += __shfl_xor(v, 2);
      v += __shfl_xor(v, 4); v += __shfl_xor(v, 8);
      ls[ms][j] = v;
    }
  if (fr == 0)
    #pragma unroll
    for (int ms = 0; ms < 4; ++ms)
      #pragma unroll
      for (int j = 0; j < 4; ++j) red[w][ms * 16 + kg * 4 + j] = ls[ms][j];
  __syncthreads();
  if (t < EH)
    il_tab[t] = 1.f / (red[0][t] + red[1][t] + red[2][t] + red[3][t]);
  __syncthreads();

  // ---- ap2 frags, 1/l folded: row h = fr, k-dim e = half*32+kg*8..+8 ----
  short8v af2[2];
  #pragma unroll
  for (int half = 0; half < 2; ++half) {
    short8v v;
    #pragma unroll
    for (int j = 0; j < 8; ++j) {
      const int e = half * 32 + kg * 8 + j;
      v[j] = f2bf(ap2_w[fr * 64 + e] * il_tab[e]);
    }
    af2[half] = v;
  }

  // ---- sweep P: P=exp(z) -> Pt -> mix2 -> write back into St (wave-local) ----
  for (int s = 0; s < 16; ++s) {
    const int krow = kbase + s * 16 + fr;
    short8v bg;
    #pragma unroll
    for (int j = 0; j < 8; ++j) bg[j] = 0;
    if (kg < 2) bg = *(const short8v*)&St[krow][kg * 8];
    #pragma unroll
    for (int ms = 0; ms < 4; ++ms) {
      const f32x4 zv = __builtin_amdgcn_mfma_f32_16x16x32_bf16(af1[ms], bg, zc, 0, 0, 0);
      const float p0 = __expf(zv[0]);
      const float p1 = __expf(zv[1]);
      const float p2 = __expf(zv[2]);
      const float p3 = __expf(zv[3]);
      *(uint32_t*)&Pt[w][fr][ms * 16 + kg * 4]     = packbf(p0, p1);
      *(uint32_t*)&Pt[w][fr][ms * 16 + kg * 4 + 2] = packbf(p2, p3);
    }
    // mix2: out[16h][16k], K = 64 e (2 chained MFMA); Pt wave-private
    f32x4 o = zc;
    const short8v pv0 = *(const short8v*)&Pt[w][fr][kg * 8];
    const short8v pv1 = *(const short8v*)&Pt[w][fr][32 + kg * 8];
    o = __builtin_amdgcn_mfma_f32_16x16x32_bf16(af2[0], pv0, o, 0, 0, 0);
    o = __builtin_amdgcn_mfma_f32_16x16x32_bf16(af2[1], pv1, o, 0, 0, 0);
    // write h = kg*4..+3 of column krow back into St (RAW-safe: value chain
    // bg -> Pt-write -> Pt-read -> o orders this after all St reads of row)
    *(uint32_t*)&St[krow][kg * 4]     = packbf(o[0] + b2[0], o[1] + b2[1]);
    *(uint32_t*)&St[krow][kg * 4 + 2] = packbf(o[2] + b2[2], o[3] + b2[3]);
  }
  __syncthreads();

  // ---- unstage: coalesced short8 stores back to Sb (in place) ----
  #pragma unroll
  for (int it = 0; it < 4; ++it) {
    const int i  = t + it * 256;
    const int k8 = (i & 127) * 8;
    const int hp = i >> 7;
    short8v o0, o1;
    #pragma unroll
    for (int j = 0; j < 8; ++j) {
      const uint32_t u = *(const uint32_t*)&St[k8 + j][2 * hp];
      o0[j] = (short)(u & 0xFFFF);
      o1[j] = (short)(u >> 16);
    }
    *(short8v*)(Sb + ((size_t)(2 * hp)     << 20) + qoff + k8) = o0;
    *(short8v*)(Sb + ((size_t)(2 * hp + 1) << 20) + qoff + k8) = o1;
  }
}

// ---------------------------------------------------------------------------
extern "C" void kernel_launch(void* const* d_in, const int* in_sizes, int n_in,
                              void* d_out, int out_size, void* d_ws, size_t ws_size,
                              hipStream_t stream)
{
  (void)in_sizes; (void)n_in; (void)out_size; (void)ws_size;

  const float* x      = (const float*)d_in[0];
  const float* qkv_w  = (const float*)d_in[1];
  const float* qkv_b  = (const float*)d_in[2];
  const float* proj_w = (const float*)d_in[3];
  const float* proj_b = (const float*)d_in[4];
  const float* ap1_w  = (const float*)d_in[5];
  const float* ap2_w  = (const float*)d_in[7];
  const float* ap2_b  = (const float*)d_in[8];
  float* out = (float*)d_out;

  // ws: xb[1M] wqb[3M] wpb[1M] qkvb[3M] Sb[16M] Vt[1M] shorts.
  // attnb reuses xb (dead after qkv GEMM).
  short* xb    = (short*)d_ws;
  short* wqb   = xb   + (size_t)(1 << 20);
  short* wpb   = wqb  + (size_t)3 * (1 << 20);
  short* qkvb  = wpb  + (size_t)(1 << 20);
  short* Sb    = qkvb + (size_t)3 * (1 << 20);
  short* Vt    = Sb   + (size_t)16 * (1 << 20);
  short* attnb = xb;

  // 0) converts + out prefill
  prep<<<dim3(3584), 256, 0, stream>>>(x, qkv_w, proj_w, proj_b,
                                       xb, wqb, wpb, out);

  // 1) qkvb = bf16(x @ qkv_w^T + qkv_b)        [1024 x 3072], K=1024
  gemm_v2<128, 1, 0><<<dim3(48, 8, 1), 256, 0, stream>>>(
      xb, DIM, 0, wqb, DIM, 0, qkvb, 3 * DIM, 0, DIM, 1.f, qkv_b);

  // 2) Sb[h] = bf16((q_h.k_h)/8), direct frags + wide stores
  scores_v2<<<dim3(16, 8, NH), 256, 0, stream>>>(qkvb, Sb);

  // 3) Vt[h][d][k] = V[h][k][d]
  transpose_v<<<dim3(32, NH), 256, 0, stream>>>(qkvb, Vt);

  // 4) fused mix1 + softmax(no-max) + mix2, in place on Sb (wide I/O)
  mix_softmax<<<dim3(S_LEN), 256, 0, stream>>>(Sb, ap1_w, ap2_w, ap2_b);

  // 5) attnb[q][h*64+d] = bf16(sum_k Pmix[h][q][k] Vt[h][d][k]), 64x64 tiles
  gemm_v2<64, 1, 0><<<dim3(1, 16, NH), 256, 0, stream>>>(
      Sb, S_LEN, (long long)S_LEN * S_LEN, Vt, S_LEN, (long long)HD * S_LEN,
      attnb, DIM, HD, S_LEN, 1.f, nullptr);

  // 6) out += attnb @ proj_w^T (bias prefilled), K-split 2, atomic
  gemm_v2<128, 2, 2><<<dim3(16, 8, 2), 256, 0, stream>>>(
      attnb, DIM, 0, wpb, DIM, 0, out, DIM, 0, DIM, 1.f, nullptr);
}